// Round 2
// baseline (283.246 us; speedup 1.0000x reference)
//
#include <hip/hip_runtime.h>
#include <hip/hip_bf16.h>
#include <math.h>

typedef __bf16 bf16_t;
typedef __bf16 bf16x8 __attribute__((ext_vector_type(8)));
typedef __bf16 bf16x4 __attribute__((ext_vector_type(4)));
typedef float  f32x4  __attribute__((ext_vector_type(4)));

#define EPSF 1e-5f
#define TAUF 1.5f

__device__ __forceinline__ float sigmoidf_(float x){ return 1.f/(1.f+__expf(-x)); }
__device__ __forceinline__ float siluf_(float x){ return x*sigmoidf_(x); }

__device__ __forceinline__ void gload_lds16(const void* g, void* l){
  __builtin_amdgcn_global_load_lds((const __attribute__((address_space(1))) unsigned int*)g,
                                   (__attribute__((address_space(3))) unsigned int*)l, 16, 0, 0);
}

// ---------------- p[b,c] = mean_hw(x) ----------------
__global__ void k_pool(const float* __restrict__ x, float* __restrict__ p){
  int bc = blockIdx.x; const float* xr = x + (size_t)bc*4096;
  float s = 0.f;
  for (int i = threadIdx.x; i < 4096; i += 256) s += xr[i];
  __shared__ float sb[4];
  for (int off=32; off; off>>=1) s += __shfl_down(s, off);
  if ((threadIdx.x & 63)==0) sb[threadIdx.x>>6] = s;
  __syncthreads();
  if (threadIdx.x==0) p[bc] = (sb[0]+sb[1]+sb[2]+sb[3]) * (1.f/4096.f);
}

// ---------------- per-b tiny MLPs ----------------
__global__ void k_small1(const float* __restrict__ p, const float* __restrict__ gc_w1,
                         const float* __restrict__ gc_w2, const float* __restrict__ cg_w1,
                         const float* __restrict__ cg_b1, const float* __restrict__ cg_w2,
                         const float* __restrict__ cg_b2,
                         float* __restrict__ gbuf, float* __restrict__ gate){
  int b = blockIdx.x; int t = threadIdx.x; // 128 threads
  __shared__ float ps[128], h1[32], pc[128], c1[16];
  ps[t] = p[b*128+t];
  __syncthreads();
  if (t < 32){ float a=0.f; for(int c=0;c<128;c++) a += ps[c]*gc_w1[t*128+c]; h1[t]=siluf_(a); }
  __syncthreads();
  float a=0.f; for(int j=0;j<32;j++) a += h1[j]*gc_w2[t*32+j];
  float g = sigmoidf_(a);
  gbuf[b*128+t] = g; pc[t] = ps[t]*g;   // mean(x*g) = g*mean(x)
  __syncthreads();
  if (t < 16){ float a2=cg_b1[t]; for(int c=0;c<128;c++) a2 += pc[c]*cg_w1[t*128+c]; c1[t]=siluf_(a2); }
  __syncthreads();
  float a3=cg_b2[t]; for(int j=0;j<16;j++) a3 += c1[j]*cg_w2[t*16+j];
  gate[b*128+t] = g * sigmoidf_(a3);
}

// ---------------- s_in: mean/max over channels of x*g (1 row / block) ----------------
__global__ void k_spatial(const float* __restrict__ x, const float* __restrict__ gbuf,
                          float* __restrict__ sin_){
  int bi = blockIdx.x; int b = bi>>6; int h = bi&63;
  int wv = threadIdx.x>>6, w = threadIdx.x&63;
  __shared__ float psum[4][64], pmax[4][64];
  float sm=0.f, mx=-1e30f;
  const float* xb = x + (((size_t)b*128 + wv*32)*64 + h)*64 + w;
  const float* gb = gbuf + b*128 + wv*32;
  #pragma unroll 4
  for (int c=0;c<32;c++){
    float v = xb[(size_t)c*4096] * gb[c];
    sm += v; mx = fmaxf(mx, v);
  }
  psum[wv][w]=sm; pmax[wv][w]=mx;
  __syncthreads();
  if (threadIdx.x < 64){
    float s = psum[0][w]+psum[1][w]+psum[2][w]+psum[3][w];
    float m = fmaxf(fmaxf(pmax[0][w],pmax[1][w]),fmaxf(pmax[2][w],pmax[3][w]));
    sin_[b*8192 + h*64 + w]        = s*(1.f/128.f);
    sin_[b*8192 + 4096 + h*64 + w] = m;
  }
}

// ---------------- x2: fused 7x7 spatial-gate + gating + quad-split store ----------------
// X2Q layout: [b][h2(4)][q(4)][68][68][8ch], original (h,w) at padded (h+2, w+2)
__global__ void __launch_bounds__(256) k_x2(
    const float* __restrict__ x, const float* __restrict__ gate,
    const float* __restrict__ sin_, const float* __restrict__ sg_w,
    bf16_t* __restrict__ x2q, float* __restrict__ pc2){
  int bi = blockIdx.x; int b = bi>>6; int h = bi&63;
  __shared__ float tile[128*65];   // 33280 B, stride-65 (conflict-free)
  __shared__ float sh_sin[980];    // [c2(2)][r(7)][col(70)]
  __shared__ float sh_sgw[98];
  __shared__ float satt_row[64];
  int tid = threadIdx.x, wv = tid>>6, lane = tid&63;
  for (int i=tid;i<980;i+=256){
    int c2 = i/490; int rr = i - c2*490; int r = rr/70; int k = rr - r*70;
    int hh = h + r - 3; int ww = k - 3;
    float v = 0.f;
    if (hh>=0 && hh<64 && ww>=0 && ww<64) v = sin_[b*8192 + c2*4096 + hh*64 + ww];
    sh_sin[i] = v;
  }
  if (tid < 98) sh_sgw[tid] = sg_w[tid];
  __syncthreads();
  if (tid < 64){
    float a = 0.f;
    #pragma unroll
    for (int c2=0;c2<2;c2++)
      #pragma unroll
      for (int r=0;r<7;r++)
        #pragma unroll
        for (int j=0;j<7;j++)
          a += sh_sin[c2*490 + r*70 + tid + j] * sh_sgw[c2*49 + r*7 + j];
    satt_row[tid] = sigmoidf_(a);
  }
  __syncthreads();
  float sa = satt_row[lane];
  // phase A: 32 independent coalesced loads -> f32 tile (no cross-lane ops)
  const float* xb = x + (((size_t)b*128 + wv*32)*64 + h)*64 + lane;
  const float* gb = gate + b*128 + wv*32;
  #pragma unroll 8
  for (int i=0;i<32;i++)
    tile[(wv*32+i)*65 + lane] = xb[(size_t)i*4096] * gb[i] * sa;
  __syncthreads();
  // phase B: quad-split bf16 store
  for (int it=0; it<4; it++){
    int idx = it*256 + tid;
    int cq = idx>>6; int w = idx&63;
    int c0 = cq*8;
    bf16x8 v;
    #pragma unroll
    for (int e=0;e<8;e++) v[e] = (bf16_t)tile[(c0+e)*65 + w];
    *(bf16x8*)(x2q + (((((size_t)b*4 + (cq>>2))*4 + (cq&3))*68 + (h+2))*68 + (w+2))*8) = v;
  }
  // phase C: per-channel row sum, one atomic per (b,c)
  if (tid < 128){
    const float* row = &tile[tid*65];
    float s = 0.f;
    #pragma unroll 8
    for (int w=0;w<64;w++) s += row[w];
    atomicAdd(&pc2[b*128+tid], s);
  }
}

// ---------------- weight prep (+ X2Q border zeroing fused) ----------------
// WCQ [ob(8)][t(9)][h2(4)][s(4)][q(4)][o16(16)][c8(8)] bf16, W'_s = base + delta_s*scale
// RCWQ [h2(4)][t(9)][n2(2)][q(4)][h16(16)][c8(8)] bf16
__global__ void k_wprep(const float* __restrict__ base_w, const float* __restrict__ delta_w,
                        const float* __restrict__ kscale, const float* __restrict__ rc_w,
                        bf16_t* __restrict__ WCQ, bf16_t* __restrict__ RCWQ,
                        bf16_t* __restrict__ x2q){
  int bx = blockIdx.x;
  if (bx >= 2448){
    // zero X2Q borders: 256 planes of [68][68][8]
    int p = bx - 2448;
    size_t base = (size_t)p*68*68*8;
    float4 z = {0.f,0.f,0.f,0.f};
    for (int i = threadIdx.x; i < 272; i += 256){
      int r = i/68; int wp = i - r*68;
      int hp = (r&1) + (r>>1)*66;
      *(float4*)(x2q + base + ((size_t)hp*68 + wp)*8) = z;
    }
    {
      int i = threadIdx.x;
      int hp = 2 + (i>>2);
      int wp = (i&1) + (i&2)*33;
      *(float4*)(x2q + base + ((size_t)hp*68 + wp)*8) = z;
    }
    return;
  }
  int i = bx*256 + threadIdx.x;
  if (i < 589824){
    int c8 = i&7; int o16 = (i>>3)&15; int q = (i>>7)&3; int s = (i>>9)&3;
    int h2 = (i>>11)&3; int r = i>>13; int t = r%9; int ob = r/9;
    int o = ob*16 + o16; int c = h2*32 + q*8 + c8;
    float v = base_w[(o*128+c)*9 + t] + delta_w[(((s*128)+o)*128 + c)*9 + t]*kscale[s*128+o];
    WCQ[i] = (bf16_t)v;
  } else if (i < 589824 + 36864){
    int j = i - 589824;
    int c8 = j&7; int h16 = (j>>3)&15; int q = (j>>7)&3; int n2 = (j>>9)&1;
    int r = j>>10; int t = r%9; int h2 = r/9;
    int hid = n2*16 + h16; int c = h2*32 + q*8 + c8;
    RCWQ[j] = (bf16_t)rc_w[(hid*128+c)*9 + t];
  }
}

// ---------------- router: strip + all-taps-resident MFMA, gf fused ----------------
// grid 512 = b(16) x rb(32 strips of 2 rows). M=128 pos, N=32 hid, K=1152.
__global__ void __launch_bounds__(256) k_router(
    const bf16_t* __restrict__ x2q, const bf16_t* __restrict__ RCWQ,
    const float* __restrict__ bn_gamma, const float* __restrict__ bn_beta,
    const float* __restrict__ bn_mean, const float* __restrict__ bn_var,
    const float* __restrict__ pc2, const float* __restrict__ rg_w,
    bf16_t* __restrict__ lfb){
  __shared__ __align__(16) char smem[44544]; // strip 4x6528=26112 + weights 18432
  __shared__ float sgf[32];
  __shared__ float spart[256];
  int tid = threadIdx.x;
  int wv = tid>>6, lane = tid&63, m16 = lane&15, q = lane>>4;
  int rb = blockIdx.x & 31, b = blockIdx.x >> 5;
  int r0 = rb*2;
  int rloc = wv&1;
  int ws0 = (wv>>1)*2;

  // fused gf = silu(mean(x2) @ rg_w^T): 256 threads = hid(32) x seg(8 of 16ch)
  {
    int hid = tid&31, seg = tid>>5;
    float a=0.f;
    #pragma unroll
    for (int j=0;j<16;j++) a += pc2[b*128 + seg*16 + j]*rg_w[hid*128 + seg*16 + j];
    spart[tid] = a;
  }

  f32x4 acc[2][2] = {};   // [n2][mt]

  #pragma unroll 1
  for (int h2=0; h2<4; h2++){
    const char* asrc = (const char*)(x2q + ((((size_t)(b*4+h2)*4 + wv)*68 + r0)*68)*8);
    #pragma unroll
    for (int j=0;j<7;j++){
      if (j*64 + lane < 408)
        gload_lds16(asrc + j*1024 + lane*16, (char*)smem + wv*6528 + j*1024);
    }
    const char* wsrc = (const char*)(RCWQ + (size_t)h2*9216) + wv*4608;
    #pragma unroll
    for (int j=0;j<5;j++){
      if (j*64 + lane < 288)
        gload_lds16(wsrc + j*1024 + lane*16, (char*)smem + 26112 + wv*4608 + j*1024);
    }
    __syncthreads();
    if (h2==0 && tid < 32){
      float s = 0.f;
      #pragma unroll
      for (int k=0;k<8;k++) s += spart[k*32+tid];
      sgf[tid] = siluf_(s*(1.f/4096.f));
    }
    #pragma unroll
    for (int t=0; t<9; t++){
      int di = t/3, dj = t - di*3;
      bf16x8 aw0 = *(const bf16x8*)((const char*)smem + 26112 + (t*2+0)*1024 + q*256 + m16*16);
      bf16x8 aw1 = *(const bf16x8*)((const char*)smem + 26112 + (t*2+1)*1024 + q*256 + m16*16);
      #pragma unroll
      for (int mt=0; mt<2; mt++){
        int wseg = ws0 + mt;
        bf16x8 bs = *(const bf16x8*)((const char*)smem + q*6528 +
                     ((rloc + 2*di)*68 + wseg*16 + m16 + 2*dj)*16);
        acc[0][mt] = __builtin_amdgcn_mfma_f32_16x16x32_bf16(aw0, bs, acc[0][mt], 0,0,0);
        acc[1][mt] = __builtin_amdgcn_mfma_f32_16x16x32_bf16(aw1, bs, acc[1][mt], 0,0,0);
      }
    }
    __syncthreads();
  }

  #pragma unroll
  for (int n2=0;n2<2;n2++){
    float aa[4], bb[4];
    #pragma unroll
    for (int i=0;i<4;i++){
      int hid = n2*16 + q*4 + i;
      float a = bn_gamma[hid]*rsqrtf(bn_var[hid]+EPSF);
      aa[i] = a;
      bb[i] = bn_beta[hid] - bn_mean[hid]*a;
    }
    #pragma unroll
    for (int mt=0;mt<2;mt++){
      bf16x4 yv;
      #pragma unroll
      for (int i=0;i<4;i++){
        int hid = n2*16 + q*4 + i;
        yv[i] = (bf16_t)(siluf_(aa[i]*acc[n2][mt][i] + bb[i]) + sgf[hid]);
      }
      size_t pos = (size_t)b*4096 + (r0+rloc)*64 + (ws0+mt)*16 + m16;
      *(bf16x4*)(lfb + pos*32 + n2*16 + q*4) = yv;
    }
  }
}

// ---------------- main dynamic conv: 12-phase deep-pipelined implicit GEMM ----------------
// grid: 512 = ob2(4) x b(16) x hb(8), 512 threads (8 waves).
// Two ob halves (N=2x16 outs x 4 experts) share one A strip. M=512, K=1152.
// Phases: 4 h2 x 3 tap-rows. Per phase: {issue A-part(2) + B-next-group(3),
// counted vmcnt (never 0 until tail), s_barrier, setprio(1), 96 MFMA, setprio(0),
// s_barrier}. A double-buffered (2x43584); B = 2-slot ring of 3-tap groups
// (2x24576) so B fetch hides under a full compute phase. LF for the epilogue
// is pre-staged into A-buffer-0 during h2=3 (its last read is h2=2).
// LDS: A0@0, A1@43584, Bring@87168, sred@136320 -> 137344 B.
__global__ void __launch_bounds__(512, 2) k_main(
    const bf16_t* __restrict__ x2q, const bf16_t* __restrict__ WCQ,
    const bf16_t* __restrict__ lfb, const float* __restrict__ gate_w,
    const float* __restrict__ gate_b, bf16_t* __restrict__ outp,
    float* __restrict__ csum, float* __restrict__ cssq){
  __shared__ __align__(16) char smem[137344];
  float* sred = (float*)(smem + 136320);

  int tid = threadIdx.x;
  int wv = tid>>6, lane = tid&63, m16 = lane&15, q = lane>>4;
  int hf = wv>>2, w4 = wv&3;        // hf: ob half, w4: row-group role
  int bx = blockIdx.x;
  int ob2 = bx >> 7; int rem = bx & 127; int b = rem >> 3; int hb = rem & 7;
  int h0 = hb*8;
  int obase = (ob2*2 + hf)*16;

  // A: wave wv stages quad (wv>>1), row-half (wv&1); part p issues j=2p,2p+1 (2 issues).
  auto STAGE_A2 = [&](int h2n, int bsel, int part){
    int quad = wv>>1, rh = wv&1;
    const char* asrc = (const char*)(x2q + ((((size_t)(b*4+h2n)*4 + quad)*68 + (h0+1+rh*5))*68)*8);
    char* adst = (char*)smem + bsel*43584 + quad*10896 + rh*5440;
    #pragma unroll
    for (int jj=0;jj<2;jj++){
      int j = part*2+jj;
      if (j*64 + lane < 340)
        gload_lds16(asrc + (j*64+lane)*16, adst + j*1024);
    }
  };
  // B: stage 3-tap group gn of h2n into ring slot (3 issues/wave, no predicate).
  auto STAGE_B3 = [&](int h2n, int gn, int slot){
    int obh = ob2*2 + hf;
    const char* wsrc = (const char*)WCQ + (size_t)(obh*9 + gn*3)*16384 + (size_t)h2n*4096;
    char* bdst = (char*)smem + 87168 + slot*24576 + hf*12288;
    #pragma unroll
    for (int j=0;j<3;j++){
      int cc = w4*3 + j;          // 0..11 chunks of 1024 B
      int tl = cc>>2, r = cc&3;
      gload_lds16(wsrc + tl*16384 + r*1024 + lane*16, bdst + cc*1024);
    }
  };
  // LF epilogue pre-stage into A-buffer-0 (4 issues/wave).
  auto STAGE_LF = [&](){
    const char* lfsrc = (const char*)(lfb + ((size_t)b*4096 + h0*64)*32);
    #pragma unroll
    for (int j=0;j<4;j++)
      gload_lds16(lfsrc + j*8192 + wv*1024 + lane*16, (char*)smem + j*8192 + wv*1024);
  };

  f32x4 acc[8][4] = {};

  int baseA[8];
  #pragma unroll
  for (int mi=0;mi<8;mi++){
    int row = w4*2 + (mi>>2); int wseg = mi&3;
    baseA[mi] = q*10896 + (row*68 + wseg*16 + m16 + 1)*16;
  }
  int baseB = q*256 + m16*16;

  // prologue: full A(0) (6 issues) + B group0 (3 issues)
  STAGE_A2(0, 0, 0); STAGE_A2(0, 0, 1); STAGE_A2(0, 0, 2);
  STAGE_B3(0, 0, 0);

  #pragma unroll 1
  for (int h2=0; h2<4; h2++){
    const char* Ab = (const char*)smem + (h2&1)*43584;
    #pragma unroll
    for (int g=0; g<3; g++){
      int slot = (h2 + g) & 1;            // P = 3*h2+g; P&1 == (h2+g)&1
      // ---- issue next-phase stages (before the wait, stay in flight) ----
      if (h2 < 3) STAGE_A2(h2+1, (h2+1)&1, g);
      if (g < 2){
        STAGE_B3(h2, g+1, slot^1);
      } else if (h2 < 3){
        STAGE_B3(h2+1, 0, slot^1);
      }
      if (g == 1 && h2 == 3) STAGE_LF();
      // ---- counted waits: everything issued BEFORE this phase has landed ----
      if (h2 < 3)      asm volatile("s_waitcnt vmcnt(5)" ::: "memory");
      else if (g == 0) asm volatile("s_waitcnt vmcnt(3)" ::: "memory");
      else if (g == 1) asm volatile("s_waitcnt vmcnt(7)" ::: "memory");
      else             asm volatile("s_waitcnt vmcnt(0)" ::: "memory");
      __builtin_amdgcn_s_barrier();

      const char* Bb = (const char*)smem + 87168 + slot*24576 + hf*12288;
      __builtin_amdgcn_s_setprio(1);
      #pragma unroll
      for (int tl=0; tl<3; tl++){
        int toff = g*1088 + tl*16;        // (di*68+dj)*16, di=g, dj=tl
        bf16x8 av[8], bv[4];
        #pragma unroll
        for (int mi=0;mi<8;mi++) av[mi] = *(const bf16x8*)(Ab + baseA[mi] + toff);
        #pragma unroll
        for (int s=0;s<4;s++)  bv[s] = *(const bf16x8*)(Bb + tl*4096 + s*1024 + baseB);
        #pragma unroll
        for (int s=0;s<4;s++){
          #pragma unroll
          for (int mi=0;mi<8;mi++)
            acc[mi][s] = __builtin_amdgcn_mfma_f32_16x16x32_bf16(av[mi], bv[s], acc[mi][s], 0,0,0);
        }
      }
      __builtin_amdgcn_s_setprio(0);
      __builtin_amdgcn_s_barrier();
    }
  }

  // ---- epilogue: gate logits + softmax + combine + GN-stats ----
  // LF already pre-staged at smem[0..32767]; gate_w (2 halves x 4 KB) at 32768.
  bf16_t* shGW = (bf16_t*)(smem + 32768);
  for (int idx = tid; idx < 4096; idx += 512){
    int hf2 = idx>>11; int n = (idx>>5)&63; int j2 = idx&31;
    shGW[idx] = (bf16_t)gate_w[((n>>4)*128 + (ob2*2+hf2)*16 + (n&15))*32 + j2];
  }
  __syncthreads();

  bf16x8 bg[4];
  #pragma unroll
  for (int kk=0;kk<4;kk++)
    bg[kk] = *(const bf16x8*)((const char*)shGW + hf*4096 + (kk*16+m16)*64 + q*16);
  float gb[4];
  #pragma unroll
  for (int kk=0;kk<4;kk++) gb[kk] = gate_b[kk*128 + obase + m16];

  const float itau = 1.f/TAUF;
  float s1 = 0.f, s2 = 0.f;
  size_t orow = ((size_t)(b*128 + obase + m16))*4096 + h0*64;
  #pragma unroll
  for (int mi=0; mi<8; mi++){
    bf16x8 avL = *(const bf16x8*)((const char*)smem + (w4*128 + mi*16 + m16)*64 + q*16);
    f32x4 zero = {};
    f32x4 lg[4];
    #pragma unroll
    for (int kk=0;kk<4;kk++)
      lg[kk] = __builtin_amdgcn_mfma_f32_16x16x32_bf16(avL, bg[kk], zero, 0,0,0);
    bf16x4 yv;
    #pragma unroll
    for (int r=0;r<4;r++){
      float l0 = (lg[0][r]+gb[0])*itau, l1 = (lg[1][r]+gb[1])*itau;
      float l2 = (lg[2][r]+gb[2])*itau, l3 = (lg[3][r]+gb[3])*itau;
      float mx = fmaxf(fmaxf(l0,l1),fmaxf(l2,l3));
      float e0=__expf(l0-mx), e1=__expf(l1-mx), e2=__expf(l2-mx), e3=__expf(l3-mx);
      float inv = 1.f/(e0+e1+e2+e3);
      float y = (e0*acc[mi][0][r] + e1*acc[mi][1][r]
               + e2*acc[mi][2][r] + e3*acc[mi][3][r])*inv;
      s1 += y; s2 += y*y;
      yv[r] = (bf16_t)y;
    }
    *(bf16x4*)(outp + orow + w4*128 + mi*16 + q*4) = yv;
  }

  s1 += __shfl_down(s1, 32); s1 += __shfl_down(s1, 16);
  s2 += __shfl_down(s2, 32); s2 += __shfl_down(s2, 16);
  if (lane < 16){ sred[wv*16 + lane] = s1; sred[128 + wv*16 + lane] = s2; }
  __syncthreads();
  if (tid < 32){
    int hf2 = tid>>4, o = tid&15;
    float a = 0.f, c = 0.f;
    #pragma unroll
    for (int k=0;k<4;k++){
      a += sred[(hf2*4+k)*16 + o];
      c += sred[128 + (hf2*4+k)*16 + o];
    }
    atomicAdd(&csum[b*128 + (ob2*2+hf2)*16 + o], a);
    atomicAdd(&cssq[b*128 + (ob2*2+hf2)*16 + o], c);
  }
}

// ---------------- GroupNorm stats + output-SE -> per-(b,o) affine ----------------
__global__ void k_small3(const float* __restrict__ csum, const float* __restrict__ cssq,
                         const float* __restrict__ gn_gamma, const float* __restrict__ gn_beta,
                         const float* __restrict__ se_w1, const float* __restrict__ se_b1,
                         const float* __restrict__ se_w2, const float* __restrict__ se_b2,
                         float* __restrict__ sca, float* __restrict__ shb){
  int b = blockIdx.x; int o = threadIdx.x; // 128
  __shared__ float s1[128], s2[128], gmu[8], grs[8], psl[128], t1[16];
  s1[o] = csum[b*128+o]; s2[o] = cssq[b*128+o];
  __syncthreads();
  if (o<8){
    float a=0.f,a2=0.f; for(int j=0;j<16;j++){ a+=s1[o*16+j]; a2+=s2[o*16+j]; }
    float mu = a*(1.f/65536.f); float var = a2*(1.f/65536.f) - mu*mu;
    gmu[o]=mu; grs[o]=rsqrtf(var+EPSF);
  }
  __syncthreads();
  int g = o>>4;
  psl[o] = (s1[o]*(1.f/4096.f) - gmu[g])*grs[g]*gn_gamma[o] + gn_beta[o];
  __syncthreads();
  if (o<16){ float a = se_b1[o]; for(int c=0;c<128;c++) a += psl[c]*se_w1[o*128+c]; t1[o]=siluf_(a); }
  __syncthreads();
  float a = se_b2[o]; for(int j=0;j<16;j++) a += t1[j]*se_w2[o*16+j];
  float sev = sigmoidf_(a);
  sca[b*128+o] = grs[g]*gn_gamma[o]*sev;
  shb[b*128+o] = (gn_beta[o] - gmu[g]*grs[g]*gn_gamma[o])*sev;
}

// ---------------- final ----------------
__global__ void k_final(const bf16_t* __restrict__ outp, const float* __restrict__ x,
                        const float* __restrict__ sca, const float* __restrict__ shb,
                        const float* __restrict__ bias, const float* __restrict__ iscale,
                        float* __restrict__ out){
  float ts = tanhf(iscale[0]);
  size_t i = ((size_t)blockIdx.x*256 + threadIdx.x)*8;
  int bo = (int)(i>>12); int o = bo&127;
  float A = sca[bo], Bv = shb[bo] + bias[o];
  bf16x8 ov = *(const bf16x8*)(outp + i);
  float4 x0 = *(const float4*)(x+i), x1 = *(const float4*)(x+i+4);
  float4 r0, r1;
  r0.x = (float)ov[0]*A + Bv + ts*x0.x;
  r0.y = (float)ov[1]*A + Bv + ts*x0.y;
  r0.z = (float)ov[2]*A + Bv + ts*x0.z;
  r0.w = (float)ov[3]*A + Bv + ts*x0.w;
  r1.x = (float)ov[4]*A + Bv + ts*x1.x;
  r1.y = (float)ov[5]*A + Bv + ts*x1.y;
  r1.z = (float)ov[6]*A + Bv + ts*x1.z;
  r1.w = (float)ov[7]*A + Bv + ts*x1.w;
  *(float4*)(out+i) = r0; *(float4*)(out+i+4) = r1;
}

extern "C" void kernel_launch(void* const* d_in, const int* in_sizes, int n_in,
                              void* d_out, int out_size, void* d_ws, size_t ws_size,
                              hipStream_t stream){
  const float* x      = (const float*)d_in[0];
  const float* base_w = (const float*)d_in[1];
  const float* delta_w= (const float*)d_in[2];
  const float* kscale = (const float*)d_in[3];
  const float* gc_w1  = (const float*)d_in[4];
  const float* gc_w2  = (const float*)d_in[5];
  const float* rc_w   = (const float*)d_in[6];
  const float* bn_g   = (const float*)d_in[7];
  const float* bn_b   = (const float*)d_in[8];
  const float* bn_m   = (const float*)d_in[9];
  const float* bn_v   = (const float*)d_in[10];
  const float* rg_w   = (const float*)d_in[11];
  const float* gate_w = (const float*)d_in[12];
  const float* gate_b = (const float*)d_in[13];
  const float* cg_w1  = (const float*)d_in[14];
  const float* cg_b1  = (const float*)d_in[15];
  const float* cg_w2  = (const float*)d_in[16];
  const float* cg_b2  = (const float*)d_in[17];
  const float* sg_w   = (const float*)d_in[18];
  const float* gn_g   = (const float*)d_in[19];
  const float* gn_b   = (const float*)d_in[20];
  const float* se_w1  = (const float*)d_in[21];
  const float* se_b1  = (const float*)d_in[22];
  const float* se_w2  = (const float*)d_in[23];
  const float* se_b2  = (const float*)d_in[24];
  const float* iscale = (const float*)d_in[25];
  const float* bias   = (const float*)d_in[26];
  float* out = (float*)d_out;

  char* ws = (char*)d_ws;
  size_t off = 0;
  auto alloc = [&](size_t bytes)->void*{ void* p = ws + off; off += (bytes + 255) & ~(size_t)255; return p; };
  bf16_t* X2Q = (bf16_t*)alloc(16ull*4*4*68*68*8*2); // quad-split padded channels-last
  bf16_t* WCQ = (bf16_t*)alloc(589824ull*2);
  bf16_t* RCWQ= (bf16_t*)alloc(36864ull*2);
  bf16_t* LF  = (bf16_t*)alloc(16ull*4096*32*2);
  bf16_t* OUTP= (bf16_t*)alloc(16ull*128*4096*2);
  float* PC2  = (float*)alloc(2048*4);               // PC2+CSUM+CSSQ contiguous
  float* CSUM = (float*)alloc(2048*4);
  float* CSSQ = (float*)alloc(2048*4);
  float* P    = (float*)alloc(2048*4);
  float* GB   = (float*)alloc(2048*4);
  float* GATE = (float*)alloc(2048*4);
  float* SIN  = (float*)alloc(16ull*8192*4);
  float* SCA  = (float*)alloc(2048*4);
  float* SHB  = (float*)alloc(2048*4);

  (void)hipMemsetAsync(PC2, 0, 3*8192, stream);  // PC2, CSUM, CSSQ

  k_wprep  <<<2704, 256, 0, stream>>>(base_w, delta_w, kscale, rc_w, WCQ, RCWQ, X2Q);
  k_pool   <<<2048, 256, 0, stream>>>(x, P);
  k_small1 <<<16,   128, 0, stream>>>(P, gc_w1, gc_w2, cg_w1, cg_b1, cg_w2, cg_b2, GB, GATE);
  k_spatial<<<1024, 256, 0, stream>>>(x, GB, SIN);
  k_x2     <<<1024, 256, 0, stream>>>(x, GATE, SIN, sg_w, X2Q, PC2);
  k_router <<<512,  256, 0, stream>>>(X2Q, RCWQ, bn_g, bn_b, bn_m, bn_v, PC2, rg_w, LF);
  k_main   <<<512,  512, 0, stream>>>(X2Q, WCQ, LF, gate_w, gate_b, OUTP, CSUM, CSSQ);
  k_small3 <<<16,   128, 0, stream>>>(CSUM, CSSQ, gn_g, gn_b, se_w1, se_b1, se_w2, se_b2, SCA, SHB);
  k_final  <<<4096, 256, 0, stream>>>(OUTP, x, SCA, SHB, bias, iscale, out);
}

// Round 3
// 258.492 us; speedup vs baseline: 1.0958x; 1.0958x over previous
//
#include <hip/hip_runtime.h>
#include <hip/hip_bf16.h>
#include <math.h>

typedef __bf16 bf16_t;
typedef __bf16 bf16x8 __attribute__((ext_vector_type(8)));
typedef __bf16 bf16x4 __attribute__((ext_vector_type(4)));
typedef float  f32x4  __attribute__((ext_vector_type(4)));

#define EPSF 1e-5f
#define TAUF 1.5f

__device__ __forceinline__ float sigmoidf_(float x){ return 1.f/(1.f+__expf(-x)); }
__device__ __forceinline__ float siluf_(float x){ return x*sigmoidf_(x); }

__device__ __forceinline__ void gload_lds16(const void* g, void* l){
  __builtin_amdgcn_global_load_lds((const __attribute__((address_space(1))) unsigned int*)g,
                                   (__attribute__((address_space(3))) unsigned int*)l, 16, 0, 0);
}

// ---------------- fused prep: weight repack + X2Q border zero + p[b,c]=mean_hw(x) ----------------
// blocks [0,2448): WCQ/RCWQ repack; [2448,2704): X2Q border zero; [2704,4752): pool.
// WCQ [ob(8)][t(9)][h2(4)][s(4)][q(4)][o16(16)][c8(8)] bf16, W'_s = base + delta_s*scale
// RCWQ [h2(4)][t(9)][n2(2)][q(4)][h16(16)][c8(8)] bf16
__global__ void k_prep(const float* __restrict__ base_w, const float* __restrict__ delta_w,
                       const float* __restrict__ kscale, const float* __restrict__ rc_w,
                       bf16_t* __restrict__ WCQ, bf16_t* __restrict__ RCWQ,
                       bf16_t* __restrict__ x2q,
                       const float* __restrict__ x, float* __restrict__ p){
  int bx = blockIdx.x;
  if (bx >= 2704){
    // pool: p[b,c] = mean_hw(x)
    int bc = bx - 2704; const float* xr = x + (size_t)bc*4096;
    float s = 0.f;
    for (int i = threadIdx.x; i < 4096; i += 256) s += xr[i];
    __shared__ float sb[4];
    for (int off=32; off; off>>=1) s += __shfl_down(s, off);
    if ((threadIdx.x & 63)==0) sb[threadIdx.x>>6] = s;
    __syncthreads();
    if (threadIdx.x==0) p[bc] = (sb[0]+sb[1]+sb[2]+sb[3]) * (1.f/4096.f);
    return;
  }
  if (bx >= 2448){
    // zero X2Q borders: 256 planes of [68][68][8]
    int pp = bx - 2448;
    size_t base = (size_t)pp*68*68*8;
    float4 z = {0.f,0.f,0.f,0.f};
    for (int i = threadIdx.x; i < 272; i += 256){
      int r = i/68; int wp = i - r*68;
      int hp = (r&1) + (r>>1)*66;
      *(float4*)(x2q + base + ((size_t)hp*68 + wp)*8) = z;
    }
    {
      int i = threadIdx.x;
      int hp = 2 + (i>>2);
      int wp = (i&1) + (i&2)*33;
      *(float4*)(x2q + base + ((size_t)hp*68 + wp)*8) = z;
    }
    return;
  }
  int i = bx*256 + threadIdx.x;
  if (i < 589824){
    int c8 = i&7; int o16 = (i>>3)&15; int q = (i>>7)&3; int s = (i>>9)&3;
    int h2 = (i>>11)&3; int r = i>>13; int t = r%9; int ob = r/9;
    int o = ob*16 + o16; int c = h2*32 + q*8 + c8;
    float v = base_w[(o*128+c)*9 + t] + delta_w[(((s*128)+o)*128 + c)*9 + t]*kscale[s*128+o];
    WCQ[i] = (bf16_t)v;
  } else if (i < 589824 + 36864){
    int j = i - 589824;
    int c8 = j&7; int h16 = (j>>3)&15; int q = (j>>7)&3; int n2 = (j>>9)&1;
    int r = j>>10; int t = r%9; int h2 = r/9;
    int hid = n2*16 + h16; int c = h2*32 + q*8 + c8;
    RCWQ[j] = (bf16_t)rc_w[(hid*128+c)*9 + t];
  }
}

// ---------------- per-b tiny MLPs ----------------
__global__ void k_small1(const float* __restrict__ p, const float* __restrict__ gc_w1,
                         const float* __restrict__ gc_w2, const float* __restrict__ cg_w1,
                         const float* __restrict__ cg_b1, const float* __restrict__ cg_w2,
                         const float* __restrict__ cg_b2,
                         float* __restrict__ gbuf, float* __restrict__ gate){
  int b = blockIdx.x; int t = threadIdx.x; // 128 threads
  __shared__ float ps[128], h1[32], pc[128], c1[16];
  ps[t] = p[b*128+t];
  __syncthreads();
  if (t < 32){ float a=0.f; for(int c=0;c<128;c++) a += ps[c]*gc_w1[t*128+c]; h1[t]=siluf_(a); }
  __syncthreads();
  float a=0.f; for(int j=0;j<32;j++) a += h1[j]*gc_w2[t*32+j];
  float g = sigmoidf_(a);
  gbuf[b*128+t] = g; pc[t] = ps[t]*g;   // mean(x*g) = g*mean(x)
  __syncthreads();
  if (t < 16){ float a2=cg_b1[t]; for(int c=0;c<128;c++) a2 += pc[c]*cg_w1[t*128+c]; c1[t]=siluf_(a2); }
  __syncthreads();
  float a3=cg_b2[t]; for(int j=0;j<16;j++) a3 += c1[j]*cg_w2[t*16+j];
  gate[b*128+t] = g * sigmoidf_(a3);
}

// ---------------- s_in: mean/max over channels of x*g (1 row / block) ----------------
__global__ void k_spatial(const float* __restrict__ x, const float* __restrict__ gbuf,
                          float* __restrict__ sin_){
  int bi = blockIdx.x; int b = bi>>6; int h = bi&63;
  int wv = threadIdx.x>>6, w = threadIdx.x&63;
  __shared__ float psum[4][64], pmax[4][64];
  float sm=0.f, mx=-1e30f;
  const float* xb = x + (((size_t)b*128 + wv*32)*64 + h)*64 + w;
  const float* gb = gbuf + b*128 + wv*32;
  #pragma unroll 4
  for (int c=0;c<32;c++){
    float v = xb[(size_t)c*4096] * gb[c];
    sm += v; mx = fmaxf(mx, v);
  }
  psum[wv][w]=sm; pmax[wv][w]=mx;
  __syncthreads();
  if (threadIdx.x < 64){
    float s = psum[0][w]+psum[1][w]+psum[2][w]+psum[3][w];
    float m = fmaxf(fmaxf(pmax[0][w],pmax[1][w]),fmaxf(pmax[2][w],pmax[3][w]));
    sin_[b*8192 + h*64 + w]        = s*(1.f/128.f);
    sin_[b*8192 + 4096 + h*64 + w] = m;
  }
}

// ---------------- x2: fused 7x7 spatial-gate + gating + quad-split store ----------------
// X2Q layout: [b][h2(4)][q(4)][68][68][8ch], original (h,w) at padded (h+2, w+2)
__global__ void __launch_bounds__(256) k_x2(
    const float* __restrict__ x, const float* __restrict__ gate,
    const float* __restrict__ sin_, const float* __restrict__ sg_w,
    bf16_t* __restrict__ x2q, float* __restrict__ pc2){
  int bi = blockIdx.x; int b = bi>>6; int h = bi&63;
  __shared__ float tile[128*65];   // 33280 B, stride-65 (conflict-free)
  __shared__ float sh_sin[980];    // [c2(2)][r(7)][col(70)]
  __shared__ float sh_sgw[98];
  __shared__ float satt_row[64];
  int tid = threadIdx.x, wv = tid>>6, lane = tid&63;
  for (int i=tid;i<980;i+=256){
    int c2 = i/490; int rr = i - c2*490; int r = rr/70; int k = rr - r*70;
    int hh = h + r - 3; int ww = k - 3;
    float v = 0.f;
    if (hh>=0 && hh<64 && ww>=0 && ww<64) v = sin_[b*8192 + c2*4096 + hh*64 + ww];
    sh_sin[i] = v;
  }
  if (tid < 98) sh_sgw[tid] = sg_w[tid];
  __syncthreads();
  if (tid < 64){
    float a = 0.f;
    #pragma unroll
    for (int c2=0;c2<2;c2++)
      #pragma unroll
      for (int r=0;r<7;r++)
        #pragma unroll
        for (int j=0;j<7;j++)
          a += sh_sin[c2*490 + r*70 + tid + j] * sh_sgw[c2*49 + r*7 + j];
    satt_row[tid] = sigmoidf_(a);
  }
  __syncthreads();
  float sa = satt_row[lane];
  // phase A: 32 independent coalesced loads -> f32 tile (no cross-lane ops)
  const float* xb = x + (((size_t)b*128 + wv*32)*64 + h)*64 + lane;
  const float* gb = gate + b*128 + wv*32;
  #pragma unroll 8
  for (int i=0;i<32;i++)
    tile[(wv*32+i)*65 + lane] = xb[(size_t)i*4096] * gb[i] * sa;
  __syncthreads();
  // phase B: quad-split bf16 store
  for (int it=0; it<4; it++){
    int idx = it*256 + tid;
    int cq = idx>>6; int w = idx&63;
    int c0 = cq*8;
    bf16x8 v;
    #pragma unroll
    for (int e=0;e<8;e++) v[e] = (bf16_t)tile[(c0+e)*65 + w];
    *(bf16x8*)(x2q + (((((size_t)b*4 + (cq>>2))*4 + (cq&3))*68 + (h+2))*68 + (w+2))*8) = v;
  }
  // phase C: per-channel row sum, one atomic per (b,c)
  if (tid < 128){
    const float* row = &tile[tid*65];
    float s = 0.f;
    #pragma unroll 8
    for (int w=0;w<64;w++) s += row[w];
    atomicAdd(&pc2[b*128+tid], s);
  }
}

// ---------------- router: strip + all-taps-resident MFMA, gf fused ----------------
// grid 512 = b(16) x rb(32 strips of 2 rows). M=128 pos, N=32 hid, K=1152.
__global__ void __launch_bounds__(256) k_router(
    const bf16_t* __restrict__ x2q, const bf16_t* __restrict__ RCWQ,
    const float* __restrict__ bn_gamma, const float* __restrict__ bn_beta,
    const float* __restrict__ bn_mean, const float* __restrict__ bn_var,
    const float* __restrict__ pc2, const float* __restrict__ rg_w,
    bf16_t* __restrict__ lfb){
  __shared__ __align__(16) char smem[44544]; // strip 4x6528=26112 + weights 18432
  __shared__ float sgf[32];
  __shared__ float spart[256];
  int tid = threadIdx.x;
  int wv = tid>>6, lane = tid&63, m16 = lane&15, q = lane>>4;
  int rb = blockIdx.x & 31, b = blockIdx.x >> 5;
  int r0 = rb*2;
  int rloc = wv&1;
  int ws0 = (wv>>1)*2;

  // fused gf = silu(mean(x2) @ rg_w^T): 256 threads = hid(32) x seg(8 of 16ch)
  {
    int hid = tid&31, seg = tid>>5;
    float a=0.f;
    #pragma unroll
    for (int j=0;j<16;j++) a += pc2[b*128 + seg*16 + j]*rg_w[hid*128 + seg*16 + j];
    spart[tid] = a;
  }

  f32x4 acc[2][2] = {};   // [n2][mt]

  #pragma unroll 1
  for (int h2=0; h2<4; h2++){
    const char* asrc = (const char*)(x2q + ((((size_t)(b*4+h2)*4 + wv)*68 + r0)*68)*8);
    #pragma unroll
    for (int j=0;j<7;j++){
      if (j*64 + lane < 408)
        gload_lds16(asrc + j*1024 + lane*16, (char*)smem + wv*6528 + j*1024);
    }
    const char* wsrc = (const char*)(RCWQ + (size_t)h2*9216) + wv*4608;
    #pragma unroll
    for (int j=0;j<5;j++){
      if (j*64 + lane < 288)
        gload_lds16(wsrc + j*1024 + lane*16, (char*)smem + 26112 + wv*4608 + j*1024);
    }
    __syncthreads();
    if (h2==0 && tid < 32){
      float s = 0.f;
      #pragma unroll
      for (int k=0;k<8;k++) s += spart[k*32+tid];
      sgf[tid] = siluf_(s*(1.f/4096.f));
    }
    #pragma unroll
    for (int t=0; t<9; t++){
      int di = t/3, dj = t - di*3;
      bf16x8 aw0 = *(const bf16x8*)((const char*)smem + 26112 + (t*2+0)*1024 + q*256 + m16*16);
      bf16x8 aw1 = *(const bf16x8*)((const char*)smem + 26112 + (t*2+1)*1024 + q*256 + m16*16);
      #pragma unroll
      for (int mt=0; mt<2; mt++){
        int wseg = ws0 + mt;
        bf16x8 bs = *(const bf16x8*)((const char*)smem + q*6528 +
                     ((rloc + 2*di)*68 + wseg*16 + m16 + 2*dj)*16);
        acc[0][mt] = __builtin_amdgcn_mfma_f32_16x16x32_bf16(aw0, bs, acc[0][mt], 0,0,0);
        acc[1][mt] = __builtin_amdgcn_mfma_f32_16x16x32_bf16(aw1, bs, acc[1][mt], 0,0,0);
      }
    }
    __syncthreads();
  }

  #pragma unroll
  for (int n2=0;n2<2;n2++){
    float aa[4], bb[4];
    #pragma unroll
    for (int i=0;i<4;i++){
      int hid = n2*16 + q*4 + i;
      float a = bn_gamma[hid]*rsqrtf(bn_var[hid]+EPSF);
      aa[i] = a;
      bb[i] = bn_beta[hid] - bn_mean[hid]*a;
    }
    #pragma unroll
    for (int mt=0;mt<2;mt++){
      bf16x4 yv;
      #pragma unroll
      for (int i=0;i<4;i++){
        int hid = n2*16 + q*4 + i;
        yv[i] = (bf16_t)(siluf_(aa[i]*acc[n2][mt][i] + bb[i]) + sgf[hid]);
      }
      size_t pos = (size_t)b*4096 + (r0+rloc)*64 + (ws0+mt)*16 + m16;
      *(bf16x4*)(lfb + pos*32 + n2*16 + q*4) = yv;
    }
  }
}

// ---------------- main dynamic conv: pipelined implicit GEMM ----------------
// grid: 512 = ob2(4) x b(16) x hb(8), 512 threads (8 waves).
// Two ob halves (N=2x16) share one A strip. M=512 (8 rows x 64 w), K=1152.
// A (43.5 KB) double-buffered, B (2x36.8 KB) single-buffered.
// Raw s_barrier + counted s_waitcnt vmcnt(N): staging loads stay in flight
// across barriers (T3+T4); no vmcnt(0) drain inside the K-loop.
// LDS: A0 @0, A1 @43584, B @87168 (+hf*36864), sred @160896 -> 161920 B.
__global__ void __launch_bounds__(512, 2) k_main(
    const bf16_t* __restrict__ x2q, const bf16_t* __restrict__ WCQ,
    const bf16_t* __restrict__ lfb, const float* __restrict__ gate_w,
    const float* __restrict__ gate_b, bf16_t* __restrict__ outp,
    float* __restrict__ csum, float* __restrict__ cssq){
  __shared__ __align__(16) char smem[161920];
  float* sred = (float*)(smem + 160896);

  int tid = threadIdx.x;
  int wv = tid>>6, lane = tid&63, m16 = lane&15, q = lane>>4;
  int hf = wv>>2, w4 = wv&3;        // hf: ob half, w4: row-group role (old wv)
  int bx = blockIdx.x;
  int ob2 = bx >> 7; int rem = bx & 127; int b = rem >> 3; int hb = rem & 7;
  int h0 = hb*8;
  int obase = (ob2*2 + hf)*16;

  // ---- staging helpers (per-wave-uniform LDS dest + lane*16, exact issue counts) ----
  // A: wave wv stages quad (wv>>1), row-half (wv&1): 340 chunks -> 6 issues/wave.
  auto STAGE_A = [&](int h2, int bsel){
    int quad = wv>>1, rh = wv&1;
    const char* asrc = (const char*)(x2q + ((((size_t)(b*4+h2)*4 + quad)*68 + (h0+1+rh*5))*68)*8);
    char* adst = (char*)smem + bsel*43584 + quad*10896 + rh*5440;
    #pragma unroll
    for (int j=0;j<6;j++){
      if (j*64 + lane < 340)
        gload_lds16(asrc + (j*64+lane)*16, adst + j*1024);
    }
  };
  // B: wave (hf,w4) stages 576 chunks of its half's WCQ[h2]: 9 issues/wave (no predicate).
  auto STAGE_B = [&](int h2){
    int obh = ob2*2 + hf;
    const char* wsrc = (const char*)WCQ + (size_t)(obh*9*4 + h2)*4096;
    char* bdst = (char*)smem + 87168 + hf*36864 + w4*9216;
    #pragma unroll
    for (int j=0;j<9;j++){
      int cc = w4*576 + j*64 + lane;
      int tap = cc>>8, r = cc&255;
      gload_lds16(wsrc + tap*16384 + r*16, bdst + j*1024);
    }
  };

  f32x4 acc[8][4] = {};

  int baseA[8];
  #pragma unroll
  for (int mi=0;mi<8;mi++){
    int row = w4*2 + (mi>>2); int wseg = mi&3;
    baseA[mi] = q*10896 + (row*68 + wseg*16 + m16 + 1)*16;
  }
  int baseB = q*256 + m16*16;

  STAGE_A(0, 0);
  STAGE_B(0);

  #pragma unroll 1
  for (int h2=0; h2<4; h2++){
    if (h2 < 3){
      STAGE_A(h2+1, (h2+1)&1);
      // oldest->newest in flight: A(h2)[6], B(h2)[9], A(h2+1)[6].
      // vmcnt(6): A(h2) and B(h2) landed; next A stays in flight.
      asm volatile("s_waitcnt vmcnt(6)" ::: "memory");
    } else {
      asm volatile("s_waitcnt vmcnt(0)" ::: "memory");
    }
    __builtin_amdgcn_s_barrier();

    const char* Ab = (const char*)smem + (h2&1)*43584;
    const char* Bb = (const char*)smem + 87168 + hf*36864;
    #pragma unroll
    for (int t=0; t<9; t++){
      int di = t/3, dj = t - di*3;
      int toff = (di*68 + dj)*16;
      bf16x8 av[8], bv[4];
      #pragma unroll
      for (int mi=0;mi<8;mi++) av[mi] = *(const bf16x8*)(Ab + baseA[mi] + toff);
      #pragma unroll
      for (int s=0;s<4;s++)  bv[s] = *(const bf16x8*)(Bb + t*4096 + s*1024 + baseB);
      #pragma unroll
      for (int s=0;s<4;s++){
        #pragma unroll
        for (int mi=0;mi<8;mi++)
          acc[mi][s] = __builtin_amdgcn_mfma_f32_16x16x32_bf16(av[mi], bv[s], acc[mi][s], 0,0,0);
      }
    }
    __builtin_amdgcn_s_barrier();
    // B is single-buffered: refill only after all waves passed the barrier.
    if (h2 < 3) STAGE_B(h2+1);
  }

  // ---- epilogue: gate logits + softmax + combine + GN-stats ----
  // LF tile (32 KB) + gate_w (2 halves x 4 KB) into LDS (alias A region).
  const char* lfsrc = (const char*)(lfb + ((size_t)b*4096 + h0*64)*32);
  #pragma unroll
  for (int j=0;j<4;j++)
    gload_lds16(lfsrc + j*8192 + wv*1024 + lane*16, (char*)smem + j*8192 + wv*1024);
  bf16_t* shGW = (bf16_t*)(smem + 32768);
  for (int idx = tid; idx < 4096; idx += 512){
    int hf2 = idx>>11; int n = (idx>>5)&63; int j2 = idx&31;
    shGW[idx] = (bf16_t)gate_w[((n>>4)*128 + (ob2*2+hf2)*16 + (n&15))*32 + j2];
  }
  __syncthreads();

  bf16x8 bg[4];
  #pragma unroll
  for (int kk=0;kk<4;kk++)
    bg[kk] = *(const bf16x8*)((const char*)shGW + hf*4096 + (kk*16+m16)*64 + q*16);
  float gb[4];
  #pragma unroll
  for (int kk=0;kk<4;kk++) gb[kk] = gate_b[kk*128 + obase + m16];

  const float itau = 1.f/TAUF;
  float s1 = 0.f, s2 = 0.f;
  size_t orow = ((size_t)(b*128 + obase + m16))*4096 + h0*64;
  #pragma unroll
  for (int mi=0; mi<8; mi++){
    bf16x8 avL = *(const bf16x8*)((const char*)smem + (w4*128 + mi*16 + m16)*64 + q*16);
    f32x4 zero = {};
    f32x4 lg[4];
    #pragma unroll
    for (int kk=0;kk<4;kk++)
      lg[kk] = __builtin_amdgcn_mfma_f32_16x16x32_bf16(avL, bg[kk], zero, 0,0,0);
    bf16x4 yv;
    #pragma unroll
    for (int r=0;r<4;r++){
      float l0 = (lg[0][r]+gb[0])*itau, l1 = (lg[1][r]+gb[1])*itau;
      float l2 = (lg[2][r]+gb[2])*itau, l3 = (lg[3][r]+gb[3])*itau;
      float mx = fmaxf(fmaxf(l0,l1),fmaxf(l2,l3));
      float e0=__expf(l0-mx), e1=__expf(l1-mx), e2=__expf(l2-mx), e3=__expf(l3-mx);
      float inv = 1.f/(e0+e1+e2+e3);
      float y = (e0*acc[mi][0][r] + e1*acc[mi][1][r]
               + e2*acc[mi][2][r] + e3*acc[mi][3][r])*inv;
      s1 += y; s2 += y*y;
      yv[r] = (bf16_t)y;
    }
    *(bf16x4*)(outp + orow + w4*128 + mi*16 + q*4) = yv;
  }

  s1 += __shfl_down(s1, 32); s1 += __shfl_down(s1, 16);
  s2 += __shfl_down(s2, 32); s2 += __shfl_down(s2, 16);
  if (lane < 16){ sred[wv*16 + lane] = s1; sred[128 + wv*16 + lane] = s2; }
  __syncthreads();
  if (tid < 32){
    int hf2 = tid>>4, o = tid&15;
    float a = 0.f, c = 0.f;
    #pragma unroll
    for (int k=0;k<4;k++){
      a += sred[(hf2*4+k)*16 + o];
      c += sred[128 + (hf2*4+k)*16 + o];
    }
    atomicAdd(&csum[b*128 + (ob2*2+hf2)*16 + o], a);
    atomicAdd(&cssq[b*128 + (ob2*2+hf2)*16 + o], c);
  }
}

// ---------------- GroupNorm stats + output-SE -> per-(b,o) affine ----------------
__global__ void k_small3(const float* __restrict__ csum, const float* __restrict__ cssq,
                         const float* __restrict__ gn_gamma, const float* __restrict__ gn_beta,
                         const float* __restrict__ se_w1, const float* __restrict__ se_b1,
                         const float* __restrict__ se_w2, const float* __restrict__ se_b2,
                         float* __restrict__ sca, float* __restrict__ shb){
  int b = blockIdx.x; int o = threadIdx.x; // 128
  __shared__ float s1[128], s2[128], gmu[8], grs[8], psl[128], t1[16];
  s1[o] = csum[b*128+o]; s2[o] = cssq[b*128+o];
  __syncthreads();
  if (o<8){
    float a=0.f,a2=0.f; for(int j=0;j<16;j++){ a+=s1[o*16+j]; a2+=s2[o*16+j]; }
    float mu = a*(1.f/65536.f); float var = a2*(1.f/65536.f) - mu*mu;
    gmu[o]=mu; grs[o]=rsqrtf(var+EPSF);
  }
  __syncthreads();
  int g = o>>4;
  psl[o] = (s1[o]*(1.f/4096.f) - gmu[g])*grs[g]*gn_gamma[o] + gn_beta[o];
  __syncthreads();
  if (o<16){ float a = se_b1[o]; for(int c=0;c<128;c++) a += psl[c]*se_w1[o*128+c]; t1[o]=siluf_(a); }
  __syncthreads();
  float a = se_b2[o]; for(int j=0;j<16;j++) a += t1[j]*se_w2[o*16+j];
  float sev = sigmoidf_(a);
  sca[b*128+o] = grs[g]*gn_gamma[o]*sev;
  shb[b*128+o] = (gn_beta[o] - gmu[g]*grs[g]*gn_gamma[o])*sev;
}

// ---------------- final ----------------
__global__ void k_final(const bf16_t* __restrict__ outp, const float* __restrict__ x,
                        const float* __restrict__ sca, const float* __restrict__ shb,
                        const float* __restrict__ bias, const float* __restrict__ iscale,
                        float* __restrict__ out){
  float ts = tanhf(iscale[0]);
  size_t i = ((size_t)blockIdx.x*256 + threadIdx.x)*8;
  int bo = (int)(i>>12); int o = bo&127;
  float A = sca[bo], Bv = shb[bo] + bias[o];
  bf16x8 ov = *(const bf16x8*)(outp + i);
  float4 x0 = *(const float4*)(x+i), x1 = *(const float4*)(x+i+4);
  float4 r0, r1;
  r0.x = (float)ov[0]*A + Bv + ts*x0.x;
  r0.y = (float)ov[1]*A + Bv + ts*x0.y;
  r0.z = (float)ov[2]*A + Bv + ts*x0.z;
  r0.w = (float)ov[3]*A + Bv + ts*x0.w;
  r1.x = (float)ov[4]*A + Bv + ts*x1.x;
  r1.y = (float)ov[5]*A + Bv + ts*x1.y;
  r1.z = (float)ov[6]*A + Bv + ts*x1.z;
  r1.w = (float)ov[7]*A + Bv + ts*x1.w;
  *(float4*)(out+i) = r0; *(float4*)(out+i+4) = r1;
}

extern "C" void kernel_launch(void* const* d_in, const int* in_sizes, int n_in,
                              void* d_out, int out_size, void* d_ws, size_t ws_size,
                              hipStream_t stream){
  const float* x      = (const float*)d_in[0];
  const float* base_w = (const float*)d_in[1];
  const float* delta_w= (const float*)d_in[2];
  const float* kscale = (const float*)d_in[3];
  const float* gc_w1  = (const float*)d_in[4];
  const float* gc_w2  = (const float*)d_in[5];
  const float* rc_w   = (const float*)d_in[6];
  const float* bn_g   = (const float*)d_in[7];
  const float* bn_b   = (const float*)d_in[8];
  const float* bn_m   = (const float*)d_in[9];
  const float* bn_v   = (const float*)d_in[10];
  const float* rg_w   = (const float*)d_in[11];
  const float* gate_w = (const float*)d_in[12];
  const float* gate_b = (const float*)d_in[13];
  const float* cg_w1  = (const float*)d_in[14];
  const float* cg_b1  = (const float*)d_in[15];
  const float* cg_w2  = (const float*)d_in[16];
  const float* cg_b2  = (const float*)d_in[17];
  const float* sg_w   = (const float*)d_in[18];
  const float* gn_g   = (const float*)d_in[19];
  const float* gn_b   = (const float*)d_in[20];
  const float* se_w1  = (const float*)d_in[21];
  const float* se_b1  = (const float*)d_in[22];
  const float* se_w2  = (const float*)d_in[23];
  const float* se_b2  = (const float*)d_in[24];
  const float* iscale = (const float*)d_in[25];
  const float* bias   = (const float*)d_in[26];
  float* out = (float*)d_out;

  char* ws = (char*)d_ws;
  size_t off = 0;
  auto alloc = [&](size_t bytes)->void*{ void* p = ws + off; off += (bytes + 255) & ~(size_t)255; return p; };
  bf16_t* X2Q = (bf16_t*)alloc(16ull*4*4*68*68*8*2); // quad-split padded channels-last
  bf16_t* WCQ = (bf16_t*)alloc(589824ull*2);
  bf16_t* RCWQ= (bf16_t*)alloc(36864ull*2);
  bf16_t* LF  = (bf16_t*)alloc(16ull*4096*32*2);
  bf16_t* OUTP= (bf16_t*)alloc(16ull*128*4096*2);
  float* PC2  = (float*)alloc(2048*4);               // PC2+CSUM+CSSQ contiguous
  float* CSUM = (float*)alloc(2048*4);
  float* CSSQ = (float*)alloc(2048*4);
  float* P    = (float*)alloc(2048*4);
  float* GB   = (float*)alloc(2048*4);
  float* GATE = (float*)alloc(2048*4);
  float* SIN  = (float*)alloc(16ull*8192*4);
  float* SCA  = (float*)alloc(2048*4);
  float* SHB  = (float*)alloc(2048*4);

  (void)hipMemsetAsync(PC2, 0, 3*8192, stream);  // PC2, CSUM, CSSQ

  k_prep   <<<4752, 256, 0, stream>>>(base_w, delta_w, kscale, rc_w, WCQ, RCWQ, X2Q, x, P);
  k_small1 <<<16,   128, 0, stream>>>(P, gc_w1, gc_w2, cg_w1, cg_b1, cg_w2, cg_b2, GB, GATE);
  k_spatial<<<1024, 256, 0, stream>>>(x, GB, SIN);
  k_x2     <<<1024, 256, 0, stream>>>(x, GATE, SIN, sg_w, X2Q, PC2);
  k_router <<<512,  256, 0, stream>>>(X2Q, RCWQ, bn_g, bn_b, bn_m, bn_v, PC2, rg_w, LF);
  k_main   <<<512,  512, 0, stream>>>(X2Q, WCQ, LF, gate_w, gate_b, OUTP, CSUM, CSSQ);
  k_small3 <<<16,   128, 0, stream>>>(CSUM, CSSQ, gn_g, gn_b, se_w1, se_b1, se_w2, se_b2, SCA, SHB);
  k_final  <<<4096, 256, 0, stream>>>(OUTP, x, SCA, SHB, bias, iscale, out);
}